// Round 6
// baseline (418.387 us; speedup 1.0000x reference)
//
#include <hip/hip_runtime.h>
#include <hip/hip_bf16.h>

#define BATCH 32768
#define TSEQ 200

typedef __attribute__((ext_vector_type(8))) short short8;
typedef __attribute__((ext_vector_type(4))) float floatx4;
typedef __attribute__((ext_vector_type(2))) float f32x2;

#if __has_builtin(__builtin_amdgcn_exp2f)
__device__ __forceinline__ float EXP2(float x) { return __builtin_amdgcn_exp2f(x); }
#else
__device__ __forceinline__ float EXP2(float x) {
    float r; asm("v_exp_f32 %0, %1" : "=v"(r) : "v"(x)); return r;
}
#endif

__device__ __forceinline__ float fast_sigmoid(float x) {
    return __builtin_amdgcn_rcpf(1.0f + EXP2(-1.4426950408889634f * x));
}
__device__ __forceinline__ float fast_tanh(float x) {
    float e = EXP2(2.8853900817779268f * x);
    return 1.0f - 2.0f * __builtin_amdgcn_rcpf(e + 1.0f);
}
__device__ __forceinline__ short f2bfs(float v) {
    __hip_bfloat16 h = __float2bfloat16(v);
    return __builtin_bit_cast(short, h);
}
__device__ __forceinline__ f32x2 splat2(float x) { f32x2 v; v[0] = x; v[1] = x; return v; }
__device__ __forceinline__ f32x2 pkfma(f32x2 a, f32x2 b, f32x2 c) {
    return __builtin_elementwise_fma(a, b, c);
}
// clamp to [-4,4] — single v_med3_f32 (±4.0 are inline consts)
__device__ __forceinline__ float clamp4(float x) {
    return __builtin_fminf(__builtin_fmaxf(x, -4.0f), 4.0f);
}
template <int K>
__device__ __forceinline__ float qb(float v) {
    int i = __builtin_bit_cast(int, v);
    int r = __builtin_amdgcn_update_dpp(i, i, K * 0x55, 0xf, 0xf, false);
    return __builtin_bit_cast(float, r);
}
// 4 reciprocals with ONE v_rcp via prefix products (inputs in [945, 11505])
__device__ __forceinline__ void rcp4(float d0, float d1, float d2, float d3,
                                     float& i0, float& i1, float& i2, float& i3) {
    float p01 = d0 * d1, p23 = d2 * d3;
    float r = __builtin_amdgcn_rcpf(p01 * p23);
    float r01 = r * p23, r23 = r * p01;
    i0 = r01 * d1; i1 = r01 * d0; i2 = r23 * d3; i3 = r23 * d2;
}
__device__ __forceinline__ void async16(void* lds, const void* g) {
    __builtin_amdgcn_global_load_lds(
        (const __attribute__((address_space(1))) unsigned int*)g,
        (__attribute__((address_space(3))) unsigned int*)lds, 16, 0, 0);
}

// ---------------- workspace layout (bytes) ----------------
// hh k-index: k' = (t>>2)*16 + q*4 + (t&3)  — quad-contiguous 32B stores
#define WS_HH  0                         // bf16 [2][B][800]
#define WS_WHB 104857600                 // bf16 [128][800] cols permuted to k'
#define WS_WLB (WS_WHB + 204800)
#define WS_W1B (WS_WLB + 204800)         // bf16 [80][256]
#define WS_W2B (WS_W1B + 40960)          // bf16 [48][96] zero-pad
#define WS_U   (WS_W2B + 9216)           // f32 [401]
#define WS_OT  (WS_U + 1616)             // f32 [2][B]
#define WS_Z   (WS_OT + 262144)          // bf16 [B][256]

struct LW { const float* p[16]; };

// ---------------- kernel 0: weight prep / folds ----------------
__global__ __launch_bounds__(256) void k_prep(
    const float* __restrict__ WH, const float* __restrict__ WL,
    const float* __restrict__ W1, const float* __restrict__ W2,
    const float* __restrict__ W3, const float* __restrict__ Wp,
    const float* __restrict__ bp, const float* __restrict__ b3,
    __hip_bfloat16* __restrict__ WHbf, __hip_bfloat16* __restrict__ WLbf,
    __hip_bfloat16* __restrict__ W1bf, __hip_bfloat16* __restrict__ W2bf,
    float* __restrict__ u)
{
    int gid = blockIdx.x * 256 + threadIdx.x;   // 400 blocks = 102400 = 128*800
    // reference col k = 4t+q  ->  k' = (t>>2)*16 + q*4 + (t&3)
    int n = gid / 800, k = gid - n * 800;
    int t = k >> 2, q = k & 3;
    int kp = (t >> 2) * 16 + q * 4 + (t & 3);
    int dst = n * 800 + kp;
    WHbf[dst] = __float2bfloat16(WH[gid]);
    WLbf[dst] = __float2bfloat16(WL[gid]);
    if (gid < 20480) W1bf[gid] = __float2bfloat16(W1[gid]);
    if (gid < 4608) {
        int rr = gid / 96, cc = gid - rr * 96;
        float v = (rr < 40 && cc < 80) ? W2[rr * 80 + cc] : 0.0f;
        W2bf[gid] = __float2bfloat16(v);
    }
    if (gid < 400) {
        float a = 0.f;
        for (int j = 0; j < 40; ++j) a = fmaf(W3[40 + j], Wp[j * 400 + gid], a);
        u[gid] = a;
    } else if (gid == 400) {
        float a = b3[0];
        for (int j = 0; j < 40; ++j) a = fmaf(W3[40 + j], bp[j], a);
        u[400] = a;
    }
}

// ---------------- kernel 1: fused 2-layer LSTM, Padé activations ----------------
// 4 lanes per (b,r). tanh via Padé[5/4]: T(y)=y(945+105y²+y⁴)/(945+420y²+15y⁴),
// y clamped to ±4 (err<2.3e-3). sigmoid(x)=0.5+0.5T(x/2), the 0.5 folded into
// weights. Gate denominators batched 4-per-v_rcp. Zero v_exp in the loop.
__global__ __launch_bounds__(256)
__attribute__((amdgpu_waves_per_eu(4, 4))) void k_lstm(
    const float* __restrict__ x, LW w, const float* __restrict__ u,
    __hip_bfloat16* __restrict__ hh, float* __restrict__ otherp)
{
    int gid = blockIdx.x * 256 + threadIdx.x;
    int q = gid & 3;
    int group = gid >> 2;
    int b = group & (BATCH - 1);
    int r = group >> 15;                 // wave-uniform

    const float* Wih0 = w.p[r * 8 + 0];
    const float* Whh0 = w.p[r * 8 + 1];
    const float* bih0 = w.p[r * 8 + 2];
    const float* bhh0 = w.p[r * 8 + 3];
    const float* Wih1 = w.p[r * 8 + 4];
    const float* Whh1 = w.p[r * 8 + 5];
    const float* bih1 = w.p[r * 8 + 6];
    const float* bhh1 = w.p[r * 8 + 7];

    // pairs: p=0 -> (i,f) [sigmoid], p=1 -> (g,o) [tanh, sigmoid]
    // sigmoid rows pre-scaled by 0.5 (half-argument identity); tanh row by 1.
    f32x2 wx0p[2], bb0p[2], bb1p[2], whh0p[2][4], wih1p[2][4], whh1p[2][4];
#pragma unroll
    for (int p = 0; p < 2; ++p) {
#pragma unroll
        for (int c = 0; c < 2; ++c) {
            int G = 2 * p + c;
            int j = 4 * G + q;
            float sc = (G == 2) ? 1.0f : 0.5f;
            wx0p[p][c] = Wih0[j] * sc;
            bb0p[p][c] = (bih0[j] + bhh0[j]) * sc;
            bb1p[p][c] = (bih1[j] + bhh1[j]) * sc;
#pragma unroll
            for (int k = 0; k < 4; ++k) {
                whh0p[p][k][c] = Whh0[j * 4 + k] * sc;
                wih1p[p][k][c] = Wih1[j * 4 + k] * sc;
                whh1p[p][k][c] = Whh1[j * 4 + k] * sc;
            }
        }
    }

    const f32x2 C105 = {105.0f, 105.0f};
    const f32x2 C945 = {945.0f, 945.0f};
    const f32x2 C420 = {420.0f, 420.0f};
    const f32x2 C15  = {15.0f, 15.0f};

    const float* xp = x + ((size_t)b * 2 + r) * TSEQ;
    const float* up = u + r * TSEQ;
    __hip_bfloat16* hp = hh + ((size_t)r * BATCH + b) * 800 + q * 4;

    float h0 = 0.f, c0 = 0.f, h1 = 0.f, c1 = 0.f, accO = 0.f;

    for (int tb = 0; tb < TSEQ; tb += 4) {
        float4 xv = *(const float4*)(xp + tb);
        float4 uv = *(const float4*)(up + tb);
        float xa[4] = {xv.x, xv.y, xv.z, xv.w};
        float ua[4] = {uv.x, uv.y, uv.z, uv.w};
        float hb[4];
#pragma unroll
        for (int j = 0; j < 4; ++j) {
            float xt = xa[j];
            accO = fmaf(xt, ua[j], accO);

            // ---- layer 0: gate pre-activations ----
            float a0 = qb<0>(h0), a1 = qb<1>(h0), a2 = qb<2>(h0), a3 = qb<3>(h0);
            f32x2 g0 = pkfma(splat2(xt), wx0p[0], bb0p[0]);
            f32x2 g1 = pkfma(splat2(xt), wx0p[1], bb0p[1]);
            g0 = pkfma(whh0p[0][0], splat2(a0), g0); g1 = pkfma(whh0p[1][0], splat2(a0), g1);
            g0 = pkfma(whh0p[0][1], splat2(a1), g0); g1 = pkfma(whh0p[1][1], splat2(a1), g1);
            g0 = pkfma(whh0p[0][2], splat2(a2), g0); g1 = pkfma(whh0p[1][2], splat2(a2), g1);
            g0 = pkfma(whh0p[0][3], splat2(a3), g0); g1 = pkfma(whh0p[1][3], splat2(a3), g1);
            // ---- Padé activations, packed num/den, batched rcp ----
            f32x2 yif, ygo;
            yif[0] = clamp4(g0[0]); yif[1] = clamp4(g0[1]);
            ygo[0] = clamp4(g1[0]); ygo[1] = clamp4(g1[1]);
            f32x2 u0 = yif * yif, u1 = ygo * ygo;
            f32x2 n0 = pkfma(u0, u0 + C105, C945);
            f32x2 n1 = pkfma(u1, u1 + C105, C945);
            f32x2 ny0 = n0 * yif, ny1 = n1 * ygo;
            f32x2 d0 = pkfma(u0, pkfma(u0, C15, C420), C945);
            f32x2 d1 = pkfma(u1, pkfma(u1, C15, C420), C945);
            float ri, rf, rg, ro;
            rcp4(d0[0], d0[1], d1[0], d1[1], ri, rf, rg, ro);
            float Ti = ny0[0] * ri, Tf = ny0[1] * rf;
            float Tg = ny1[0] * rg, To = ny1[1] * ro;
            float ig = fmaf(0.5f, Ti, 0.5f);
            float fg = fmaf(0.5f, Tf, 0.5f);
            float og = fmaf(0.5f, To, 0.5f);
            c0 = fmaf(fg, c0, ig * Tg);
            float yc = clamp4(c0), uc = yc * yc;
            float nc = fmaf(uc, uc + 105.0f, 945.0f);
            float dc = fmaf(uc, fmaf(uc, 15.0f, 420.0f), 945.0f);
            h0 = og * yc * nc * __builtin_amdgcn_rcpf(dc);

            // ---- layer 1 ----
            float p0 = qb<0>(h0), p1 = qb<1>(h0), p2 = qb<2>(h0), p3 = qb<3>(h0);
            float q0 = qb<0>(h1), q1 = qb<1>(h1), q2 = qb<2>(h1), q3 = qb<3>(h1);
            g0 = bb1p[0]; g1 = bb1p[1];
            g0 = pkfma(wih1p[0][0], splat2(p0), g0); g1 = pkfma(wih1p[1][0], splat2(p0), g1);
            g0 = pkfma(wih1p[0][1], splat2(p1), g0); g1 = pkfma(wih1p[1][1], splat2(p1), g1);
            g0 = pkfma(wih1p[0][2], splat2(p2), g0); g1 = pkfma(wih1p[1][2], splat2(p2), g1);
            g0 = pkfma(wih1p[0][3], splat2(p3), g0); g1 = pkfma(wih1p[1][3], splat2(p3), g1);
            g0 = pkfma(whh1p[0][0], splat2(q0), g0); g1 = pkfma(whh1p[1][0], splat2(q0), g1);
            g0 = pkfma(whh1p[0][1], splat2(q1), g0); g1 = pkfma(whh1p[1][1], splat2(q1), g1);
            g0 = pkfma(whh1p[0][2], splat2(q2), g0); g1 = pkfma(whh1p[1][2], splat2(q2), g1);
            g0 = pkfma(whh1p[0][3], splat2(q3), g0); g1 = pkfma(whh1p[1][3], splat2(q3), g1);
            yif[0] = clamp4(g0[0]); yif[1] = clamp4(g0[1]);
            ygo[0] = clamp4(g1[0]); ygo[1] = clamp4(g1[1]);
            u0 = yif * yif; u1 = ygo * ygo;
            n0 = pkfma(u0, u0 + C105, C945);
            n1 = pkfma(u1, u1 + C105, C945);
            ny0 = n0 * yif; ny1 = n1 * ygo;
            d0 = pkfma(u0, pkfma(u0, C15, C420), C945);
            d1 = pkfma(u1, pkfma(u1, C15, C420), C945);
            rcp4(d0[0], d0[1], d1[0], d1[1], ri, rf, rg, ro);
            Ti = ny0[0] * ri; Tf = ny0[1] * rf;
            Tg = ny1[0] * rg; To = ny1[1] * ro;
            ig = fmaf(0.5f, Ti, 0.5f);
            fg = fmaf(0.5f, Tf, 0.5f);
            og = fmaf(0.5f, To, 0.5f);
            c1 = fmaf(fg, c1, ig * Tg);
            yc = clamp4(c1); uc = yc * yc;
            nc = fmaf(uc, uc + 105.0f, 945.0f);
            dc = fmaf(uc, fmaf(uc, 15.0f, 420.0f), 945.0f);
            h1 = og * yc * nc * __builtin_amdgcn_rcpf(dc);
            hb[j] = h1;
        }
        ushort4 pk;
        pk.x = (unsigned short)f2bfs(hb[0]);
        pk.y = (unsigned short)f2bfs(hb[1]);
        pk.z = (unsigned short)f2bfs(hb[2]);
        pk.w = (unsigned short)f2bfs(hb[3]);
        *(ushort4*)(hp + tb * 4) = pk;   // k' = tb*4 + q*4 + 0..3; quad = 32B contig
    }
    if (q == 0) otherp[(size_t)r * BATCH + b] = accO;
}

// ---------------- kernel 2: barrier-free register GEMM ----------------
// z[row][f*128+n] = tanh(hh_f[row,:] . W_f[n,:] + b[n]);  K=800 over k'.
// grid (512, 2); 4 waves/block; wave = 16 rows x 128 cols. No LDS, no syncs.
__global__ __launch_bounds__(256) void k_gemm(
    const __hip_bfloat16* __restrict__ hh,
    const __hip_bfloat16* __restrict__ WHbf, const __hip_bfloat16* __restrict__ WLbf,
    const float* __restrict__ bH, const float* __restrict__ bL,
    __hip_bfloat16* __restrict__ zws)
{
    int tid = threadIdx.x;
    int f = blockIdx.y;
    int wv = tid >> 6, lane = tid & 63, l15 = lane & 15, quad = lane >> 4;
    int m0 = blockIdx.x * 64 + wv * 16;

    const __hip_bfloat16* Wb = f ? WLbf : WHbf;
    const float* bias = f ? bL : bH;
    const short8* ap = (const short8*)(const void*)
        (hh + (size_t)f * BATCH * 800 + (size_t)(m0 + l15) * 800 + quad * 8);
    const short8* bp0 = (const short8*)(const void*)
        (Wb + (size_t)l15 * 800 + quad * 8);

    floatx4 acc[8] = {};
#pragma unroll 2
    for (int kc = 0; kc < 25; ++kc) {
        short8 af = ap[kc * 4];
#pragma unroll
        for (int nt = 0; nt < 8; ++nt) {
            short8 bfr = bp0[(size_t)nt * 1600 + kc * 4];   // +nt*16 rows
            acc[nt] = __builtin_amdgcn_mfma_f32_16x16x32_bf16(af, bfr, acc[nt], 0, 0, 0);
        }
    }

#pragma unroll
    for (int nt = 0; nt < 8; ++nt) {
        int n = nt * 16 + l15;
        float bb = bias[n];
#pragma unroll
        for (int rg = 0; rg < 4; ++rg) {
            int row = m0 + quad * 4 + rg;
            zws[(size_t)row * 256 + f * 128 + n] =
                __float2bfloat16(fast_tanh(acc[nt][rg] + bb));
        }
    }
}

// ---------------- kernel 3: MLP tail on z ----------------
__global__ __launch_bounds__(256) void k_tail(
    const __hip_bfloat16* __restrict__ zws,
    const __hip_bfloat16* __restrict__ W1bf, const __hip_bfloat16* __restrict__ W2bf,
    const float* __restrict__ b1, const float* __restrict__ b2,
    const float* __restrict__ W3, const float* __restrict__ u,
    const float* __restrict__ otherp, float* __restrict__ out)
{
    __shared__ short z1sh[64 * 104];
    __shared__ float z2sh[64 * 49];
    int tid = threadIdx.x;
    int wv = tid >> 6, lane = tid & 63, l15 = lane & 15, quad = lane >> 4;
    int m0 = blockIdx.x * 64;

    for (int i = tid; i < 64 * 24; i += 256) {
        int rr = i / 24, cc = 80 + (i - rr * 24);
        z1sh[rr * 104 + cc] = 0;
    }

    // z1 = tanh(z @ W1.T + b1)   M=64 K=256 N=80
    {
        floatx4 acc[5] = {};
#pragma unroll
        for (int kc = 0; kc < 8; ++kc) {
            short8 af = *(const short8*)(const void*)
                (zws + (size_t)(m0 + wv * 16 + l15) * 256 + kc * 32 + quad * 8);
#pragma unroll
            for (int nt = 0; nt < 5; ++nt) {
                short8 bfr = *(const short8*)(const void*)
                    (W1bf + (size_t)(nt * 16 + l15) * 256 + kc * 32 + quad * 8);
                acc[nt] = __builtin_amdgcn_mfma_f32_16x16x32_bf16(af, bfr, acc[nt], 0, 0, 0);
            }
        }
#pragma unroll
        for (int nt = 0; nt < 5; ++nt) {
            int n = nt * 16 + l15;
            float bb = b1[n];
#pragma unroll
            for (int rg = 0; rg < 4; ++rg) {
                int ml = wv * 16 + quad * 4 + rg;
                z1sh[ml * 104 + n] = f2bfs(fast_tanh(acc[nt][rg] + bb));
            }
        }
    }
    __syncthreads();

    // z2 = tanh(z1 @ W2.T + b2)  M=64 K=96(pad) N=48(keep 40)
    {
        floatx4 acc[3] = {};
#pragma unroll
        for (int kc = 0; kc < 3; ++kc) {
            short8 af = *(const short8*)(const void*)
                &z1sh[(wv * 16 + l15) * 104 + kc * 32 + quad * 8];
#pragma unroll
            for (int nt = 0; nt < 3; ++nt) {
                short8 bfr = *(const short8*)(const void*)
                    (W2bf + (size_t)(nt * 16 + l15) * 96 + kc * 32 + quad * 8);
                acc[nt] = __builtin_amdgcn_mfma_f32_16x16x32_bf16(af, bfr, acc[nt], 0, 0, 0);
            }
        }
#pragma unroll
        for (int nt = 0; nt < 3; ++nt) {
            int n = nt * 16 + l15;
            if (n < 40) {
                float bb = b2[n];
#pragma unroll
                for (int rg = 0; rg < 4; ++rg) {
                    int ml = wv * 16 + quad * 4 + rg;
                    z2sh[ml * 49 + n] = fast_tanh(acc[nt][rg] + bb);
                }
            }
        }
    }
    __syncthreads();

    if (tid < 64) {
        int grow = m0 + tid;
        float s = u[400] + otherp[grow] + otherp[BATCH + grow];
        for (int j = 0; j < 40; ++j) s = fmaf(z2sh[tid * 49 + j], W3[j], s);
        out[grow] = fast_sigmoid(s);
    }
}

extern "C" void kernel_launch(void* const* d_in, const int* in_sizes, int n_in,
                              void* d_out, int out_size, void* d_ws, size_t ws_size,
                              hipStream_t stream)
{
    const float* x = (const float*)d_in[0];
    LW w;
    for (int i = 0; i < 16; ++i) w.p[i] = (const float*)d_in[1 + i];
    const float* Wp = (const float*)d_in[17];
    const float* bp = (const float*)d_in[18];
    const float* WH = (const float*)d_in[19];
    const float* bH = (const float*)d_in[20];
    const float* WL = (const float*)d_in[21];
    const float* bL = (const float*)d_in[22];
    const float* W1 = (const float*)d_in[23];
    const float* b1 = (const float*)d_in[24];
    const float* W2 = (const float*)d_in[25];
    const float* b2 = (const float*)d_in[26];
    const float* W3 = (const float*)d_in[27];
    const float* b3 = (const float*)d_in[28];

    char* ws = (char*)d_ws;
    __hip_bfloat16* hh   = (__hip_bfloat16*)(ws + WS_HH);
    __hip_bfloat16* WHbf = (__hip_bfloat16*)(ws + WS_WHB);
    __hip_bfloat16* WLbf = (__hip_bfloat16*)(ws + WS_WLB);
    __hip_bfloat16* W1bf = (__hip_bfloat16*)(ws + WS_W1B);
    __hip_bfloat16* W2bf = (__hip_bfloat16*)(ws + WS_W2B);
    float* u      = (float*)(ws + WS_U);
    float* otherp = (float*)(ws + WS_OT);
    __hip_bfloat16* zws = (__hip_bfloat16*)(ws + WS_Z);
    float* out = (float*)d_out;

    k_prep<<<400, 256, 0, stream>>>(WH, WL, W1, W2, W3, Wp, bp, b3,
                                    WHbf, WLbf, W1bf, W2bf, u);
    k_lstm<<<1024, 256, 0, stream>>>(x, w, u, hh, otherp);
    k_gemm<<<dim3(512, 2), 256, 0, stream>>>(hh, WHbf, WLbf, bH, bL, zws);
    k_tail<<<512, 256, 0, stream>>>(zws, W1bf, W2bf, b1, b2, W3, u, otherp, out);
}

// Round 7
// 335.548 us; speedup vs baseline: 1.2469x; 1.2469x over previous
//
#include <hip/hip_runtime.h>
#include <hip/hip_bf16.h>

#define BATCH 32768
#define TSEQ 200

typedef __attribute__((ext_vector_type(8))) short short8;
typedef __attribute__((ext_vector_type(4))) float floatx4;
typedef __attribute__((ext_vector_type(2))) float f32x2;

#if __has_builtin(__builtin_amdgcn_exp2f)
__device__ __forceinline__ float EXP2(float x) { return __builtin_amdgcn_exp2f(x); }
#else
__device__ __forceinline__ float EXP2(float x) {
    float r; asm("v_exp_f32 %0, %1" : "=v"(r) : "v"(x)); return r;
}
#endif
__device__ __forceinline__ float RCP(float x) { return __builtin_amdgcn_rcpf(x); }

__device__ __forceinline__ float fast_sigmoid(float x) {
    return RCP(1.0f + EXP2(-1.4426950408889634f * x));
}
__device__ __forceinline__ float fast_tanh(float x) {
    float e = EXP2(2.8853900817779268f * x);
    return 1.0f - 2.0f * RCP(e + 1.0f);
}
__device__ __forceinline__ short f2bfs(float v) {
    __hip_bfloat16 h = __float2bfloat16(v);
    return __builtin_bit_cast(short, h);
}
__device__ __forceinline__ f32x2 splat2(float x) { f32x2 v; v[0] = x; v[1] = x; return v; }
__device__ __forceinline__ f32x2 pkfma(f32x2 a, f32x2 b, f32x2 c) {
    return __builtin_elementwise_fma(a, b, c);
}
template <int K>
__device__ __forceinline__ float qb(float v) {
    int i = __builtin_bit_cast(int, v);
    int r = __builtin_amdgcn_update_dpp(i, i, K * 0x55, 0xf, 0xf, false);
    return __builtin_bit_cast(float, r);
}
__device__ __forceinline__ void async16(void* lds, const void* g) {
    __builtin_amdgcn_global_load_lds(
        (const __attribute__((address_space(1))) unsigned int*)g,
        (__attribute__((address_space(3))) unsigned int*)lds, 16, 0, 0);
}

#define S_SIG (-1.4426950408889634f)   // sigmoid rows: 2^(S_SIG*g) = e^-g
#define S_TANH (2.8853900817779268f)   // tanh rows:    2^(S_TANH*g) = e^(2g)

// ---------------- workspace layout (bytes) ----------------
// hh k-index: k' = (t>>2)*16 + q*4 + (t&3)  — quad-contiguous 32B stores
#define WS_HH  0                         // bf16 [2][B][800]
#define WS_WHB 104857600                 // bf16 [128][800] cols permuted to k'
#define WS_WLB (WS_WHB + 204800)
#define WS_W1B (WS_WLB + 204800)         // bf16 [80][256]
#define WS_W2B (WS_W1B + 40960)          // bf16 [48][96] zero-pad
#define WS_U   (WS_W2B + 9216)           // f32 [401]
#define WS_OT  (WS_U + 1616)             // f32 [2][B]
#define WS_Z   (WS_OT + 262144)          // bf16 [B][256]

struct LW { const float* p[16]; };

// ---------------- kernel 0: weight prep / folds ----------------
__global__ __launch_bounds__(256) void k_prep(
    const float* __restrict__ WH, const float* __restrict__ WL,
    const float* __restrict__ W1, const float* __restrict__ W2,
    const float* __restrict__ W3, const float* __restrict__ Wp,
    const float* __restrict__ bp, const float* __restrict__ b3,
    __hip_bfloat16* __restrict__ WHbf, __hip_bfloat16* __restrict__ WLbf,
    __hip_bfloat16* __restrict__ W1bf, __hip_bfloat16* __restrict__ W2bf,
    float* __restrict__ u)
{
    int gid = blockIdx.x * 256 + threadIdx.x;   // 400 blocks = 102400 = 128*800
    int n = gid / 800, k = gid - n * 800;
    int t = k >> 2, q = k & 3;
    int kp = (t >> 2) * 16 + q * 4 + (t & 3);
    int dst = n * 800 + kp;
    WHbf[dst] = __float2bfloat16(WH[gid]);
    WLbf[dst] = __float2bfloat16(WL[gid]);
    if (gid < 20480) W1bf[gid] = __float2bfloat16(W1[gid]);
    if (gid < 4608) {
        int rr = gid / 96, cc = gid - rr * 96;
        float v = (rr < 40 && cc < 80) ? W2[rr * 80 + cc] : 0.0f;
        W2bf[gid] = __float2bfloat16(v);
    }
    if (gid < 400) {
        float a = 0.f;
        for (int j = 0; j < 40; ++j) a = fmaf(W3[40 + j], Wp[j * 400 + gid], a);
        u[gid] = a;
    } else if (gid == 400) {
        float a = b3[0];
        for (int j = 0; j < 40; ++j) a = fmaf(W3[40 + j], bp[j], a);
        u[400] = a;
    }
}

// ---------------- kernel 1: fused 2-layer LSTM (both rnns) ----------------
// 4 lanes per (b,r); DPP quad broadcasts; pkfma gate dots; plain per-gate
// exp2/rcp activations (trans pipe is cheap — R5 post-mortem).
__global__ __launch_bounds__(256)
__attribute__((amdgpu_waves_per_eu(4, 4))) void k_lstm(
    const float* __restrict__ x, LW w, const float* __restrict__ u,
    __hip_bfloat16* __restrict__ hh, float* __restrict__ otherp)
{
    int gid = blockIdx.x * 256 + threadIdx.x;
    int q = gid & 3;
    int group = gid >> 2;
    int b = group & (BATCH - 1);
    int r = group >> 15;                 // wave-uniform

    const float* Wih0 = w.p[r * 8 + 0];
    const float* Whh0 = w.p[r * 8 + 1];
    const float* bih0 = w.p[r * 8 + 2];
    const float* bhh0 = w.p[r * 8 + 3];
    const float* Wih1 = w.p[r * 8 + 4];
    const float* Whh1 = w.p[r * 8 + 5];
    const float* bih1 = w.p[r * 8 + 6];
    const float* bhh1 = w.p[r * 8 + 7];

    // pairs: p=0 -> (i,f) [sigmoid], p=1 -> (g,o) [tanh, sigmoid]
    f32x2 wx0p[2], bb0p[2], bb1p[2], whh0p[2][4], wih1p[2][4], whh1p[2][4];
#pragma unroll
    for (int p = 0; p < 2; ++p) {
#pragma unroll
        for (int c = 0; c < 2; ++c) {
            int G = 2 * p + c;
            int j = 4 * G + q;
            float sc = (G == 2) ? S_TANH : S_SIG;
            wx0p[p][c] = Wih0[j] * sc;
            bb0p[p][c] = (bih0[j] + bhh0[j]) * sc;
            bb1p[p][c] = (bih1[j] + bhh1[j]) * sc;
#pragma unroll
            for (int k = 0; k < 4; ++k) {
                whh0p[p][k][c] = Whh0[j * 4 + k] * sc;
                wih1p[p][k][c] = Wih1[j * 4 + k] * sc;
                whh1p[p][k][c] = Whh1[j * 4 + k] * sc;
            }
        }
    }

    const float* xp = x + ((size_t)b * 2 + r) * TSEQ;
    const float* up = u + r * TSEQ;
    __hip_bfloat16* hp = hh + ((size_t)r * BATCH + b) * 800 + q * 4;

    float h0 = 0.f, c0 = 0.f, h1 = 0.f, c1 = 0.f, accO = 0.f;

    for (int tb = 0; tb < TSEQ; tb += 4) {
        float4 xv = *(const float4*)(xp + tb);
        float4 uv = *(const float4*)(up + tb);
        float xa[4] = {xv.x, xv.y, xv.z, xv.w};
        float ua[4] = {uv.x, uv.y, uv.z, uv.w};
        float hb[4];
#pragma unroll
        for (int j = 0; j < 4; ++j) {
            float xt = xa[j];
            accO = fmaf(xt, ua[j], accO);

            // ---- layer 0 ----
            float a0 = qb<0>(h0), a1 = qb<1>(h0), a2 = qb<2>(h0), a3 = qb<3>(h0);
            f32x2 g0 = pkfma(splat2(xt), wx0p[0], bb0p[0]);
            f32x2 g1 = pkfma(splat2(xt), wx0p[1], bb0p[1]);
            g0 = pkfma(whh0p[0][0], splat2(a0), g0); g1 = pkfma(whh0p[1][0], splat2(a0), g1);
            g0 = pkfma(whh0p[0][1], splat2(a1), g0); g1 = pkfma(whh0p[1][1], splat2(a1), g1);
            g0 = pkfma(whh0p[0][2], splat2(a2), g0); g1 = pkfma(whh0p[1][2], splat2(a2), g1);
            g0 = pkfma(whh0p[0][3], splat2(a3), g0); g1 = pkfma(whh0p[1][3], splat2(a3), g1);
            float ig = RCP(1.0f + EXP2(g0[0]));          // e^-g pre-scaled
            float fg = RCP(1.0f + EXP2(g0[1]));
            float og = RCP(1.0f + EXP2(g1[1]));
            float tg = 1.0f - 2.0f * RCP(EXP2(g1[0]) + 1.0f);   // tanh, e^2g pre-scaled
            c0 = fmaf(fg, c0, ig * tg);
            float th0 = 1.0f - 2.0f * RCP(EXP2(S_TANH * c0) + 1.0f);
            h0 = og * th0;

            // ---- layer 1 ----
            float p0 = qb<0>(h0), p1 = qb<1>(h0), p2 = qb<2>(h0), p3 = qb<3>(h0);
            float q0 = qb<0>(h1), q1 = qb<1>(h1), q2 = qb<2>(h1), q3 = qb<3>(h1);
            g0 = bb1p[0]; g1 = bb1p[1];
            g0 = pkfma(wih1p[0][0], splat2(p0), g0); g1 = pkfma(wih1p[1][0], splat2(p0), g1);
            g0 = pkfma(wih1p[0][1], splat2(p1), g0); g1 = pkfma(wih1p[1][1], splat2(p1), g1);
            g0 = pkfma(wih1p[0][2], splat2(p2), g0); g1 = pkfma(wih1p[1][2], splat2(p2), g1);
            g0 = pkfma(wih1p[0][3], splat2(p3), g0); g1 = pkfma(wih1p[1][3], splat2(p3), g1);
            g0 = pkfma(whh1p[0][0], splat2(q0), g0); g1 = pkfma(whh1p[1][0], splat2(q0), g1);
            g0 = pkfma(whh1p[0][1], splat2(q1), g0); g1 = pkfma(whh1p[1][1], splat2(q1), g1);
            g0 = pkfma(whh1p[0][2], splat2(q2), g0); g1 = pkfma(whh1p[1][2], splat2(q2), g1);
            g0 = pkfma(whh1p[0][3], splat2(q3), g0); g1 = pkfma(whh1p[1][3], splat2(q3), g1);
            ig = RCP(1.0f + EXP2(g0[0]));
            fg = RCP(1.0f + EXP2(g0[1]));
            og = RCP(1.0f + EXP2(g1[1]));
            tg = 1.0f - 2.0f * RCP(EXP2(g1[0]) + 1.0f);
            c1 = fmaf(fg, c1, ig * tg);
            float th1 = 1.0f - 2.0f * RCP(EXP2(S_TANH * c1) + 1.0f);
            h1 = og * th1;
            hb[j] = h1;
        }
        ushort4 pk;
        pk.x = (unsigned short)f2bfs(hb[0]);
        pk.y = (unsigned short)f2bfs(hb[1]);
        pk.z = (unsigned short)f2bfs(hb[2]);
        pk.w = (unsigned short)f2bfs(hb[3]);
        *(ushort4*)(hp + tb * 4) = pk;   // k' = tb*4 + q*4 + 0..3; quad = 32B contig
    }
    if (q == 0) otherp[(size_t)r * BATCH + b] = accO;
}

// ---------------- kernel 2: pipelined bf16 GEMM  z = tanh(hh @ W.T + b) ----------------
// grid (256, 2): 128 rows x 128 cols, K=800 in chunks of 32, LDS double-buffered.
__global__ __launch_bounds__(256) void k_gemm(
    const __hip_bfloat16* __restrict__ hh,
    const __hip_bfloat16* __restrict__ WHbf, const __hip_bfloat16* __restrict__ WLbf,
    const float* __restrict__ bH, const float* __restrict__ bL,
    __hip_bfloat16* __restrict__ zws)
{
    __shared__ __hip_bfloat16 As[2][128 * 32];
    __shared__ __hip_bfloat16 Bs[2][128 * 32];
    int tid = threadIdx.x;
    int f = blockIdx.y;
    int m0 = blockIdx.x * 128;
    const __hip_bfloat16* A = hh + (size_t)f * BATCH * 800 + (size_t)m0 * 800;
    const __hip_bfloat16* Wb = f ? WLbf : WHbf;
    const float* bias = f ? bL : bH;

    int wv = tid >> 6, lane = tid & 63, l15 = lane & 15, quad = lane >> 4;
    const __hip_bfloat16* ga = A + (size_t)(tid >> 2) * 800 + (tid & 3) * 8;
    const __hip_bfloat16* gb = Wb + (size_t)(tid >> 2) * 800 + (tid & 3) * 8;

    floatx4 acc[2][8] = {};

#define PREFETCH(kc, buf)                                              \
    do {                                                               \
        __hip_bfloat16* la = &As[buf][wv * 512];                       \
        __hip_bfloat16* lb = &Bs[buf][wv * 512];                       \
        async16(la,        ga + (kc) * 32);                            \
        async16(lb,        gb + (kc) * 32);                            \
        async16(la + 2048, ga + 64 * 800 + (kc) * 32);                 \
        async16(lb + 2048, gb + 64 * 800 + (kc) * 32);                 \
    } while (0)

    PREFETCH(0, 0);
    for (int kc = 0; kc < 25; ++kc) {
        __syncthreads();
        if (kc < 24) PREFETCH(kc + 1, (kc + 1) & 1);
        int buf = kc & 1;
        short8 af0 = *(const short8*)(const void*)&As[buf][(wv * 32 + l15) * 32 + quad * 8];
        short8 af1 = *(const short8*)(const void*)&As[buf][(wv * 32 + 16 + l15) * 32 + quad * 8];
#pragma unroll
        for (int nt = 0; nt < 8; ++nt) {
            short8 bfr = *(const short8*)(const void*)&Bs[buf][(nt * 16 + l15) * 32 + quad * 8];
            acc[0][nt] = __builtin_amdgcn_mfma_f32_16x16x32_bf16(af0, bfr, acc[0][nt], 0, 0, 0);
            acc[1][nt] = __builtin_amdgcn_mfma_f32_16x16x32_bf16(af1, bfr, acc[1][nt], 0, 0, 0);
        }
    }
#undef PREFETCH

    float bv[8];
#pragma unroll
    for (int nt = 0; nt < 8; ++nt) bv[nt] = bias[nt * 16 + l15];
#pragma unroll
    for (int mt = 0; mt < 2; ++mt)
#pragma unroll
        for (int nt = 0; nt < 8; ++nt)
#pragma unroll
            for (int rg = 0; rg < 4; ++rg) {
                int row = m0 + wv * 32 + mt * 16 + quad * 4 + rg;
                int col = f * 128 + nt * 16 + l15;
                zws[(size_t)row * 256 + col] =
                    __float2bfloat16(fast_tanh(acc[mt][nt][rg] + bv[nt]));
            }
}

// ---------------- kernel 3: MLP tail on z ----------------
__global__ __launch_bounds__(256) void k_tail(
    const __hip_bfloat16* __restrict__ zws,
    const __hip_bfloat16* __restrict__ W1bf, const __hip_bfloat16* __restrict__ W2bf,
    const float* __restrict__ b1, const float* __restrict__ b2,
    const float* __restrict__ W3, const float* __restrict__ u,
    const float* __restrict__ otherp, float* __restrict__ out)
{
    __shared__ short z1sh[64 * 104];
    __shared__ float z2sh[64 * 49];
    int tid = threadIdx.x;
    int wv = tid >> 6, lane = tid & 63, l15 = lane & 15, quad = lane >> 4;
    int m0 = blockIdx.x * 64;

    for (int i = tid; i < 64 * 24; i += 256) {
        int rr = i / 24, cc = 80 + (i - rr * 24);
        z1sh[rr * 104 + cc] = 0;
    }

    // z1 = tanh(z @ W1.T + b1)   M=64 K=256 N=80
    {
        floatx4 acc[5] = {};
#pragma unroll
        for (int kc = 0; kc < 8; ++kc) {
            short8 af = *(const short8*)(const void*)
                (zws + (size_t)(m0 + wv * 16 + l15) * 256 + kc * 32 + quad * 8);
#pragma unroll
            for (int nt = 0; nt < 5; ++nt) {
                short8 bfr = *(const short8*)(const void*)
                    (W1bf + (size_t)(nt * 16 + l15) * 256 + kc * 32 + quad * 8);
                acc[nt] = __builtin_amdgcn_mfma_f32_16x16x32_bf16(af, bfr, acc[nt], 0, 0, 0);
            }
        }
#pragma unroll
        for (int nt = 0; nt < 5; ++nt) {
            int n = nt * 16 + l15;
            float bb = b1[n];
#pragma unroll
            for (int rg = 0; rg < 4; ++rg) {
                int ml = wv * 16 + quad * 4 + rg;
                z1sh[ml * 104 + n] = f2bfs(fast_tanh(acc[nt][rg] + bb));
            }
        }
    }
    __syncthreads();

    // z2 = tanh(z1 @ W2.T + b2)  M=64 K=96(pad) N=48(keep 40)
    {
        floatx4 acc[3] = {};
#pragma unroll
        for (int kc = 0; kc < 3; ++kc) {
            short8 af = *(const short8*)(const void*)
                &z1sh[(wv * 16 + l15) * 104 + kc * 32 + quad * 8];
#pragma unroll
            for (int nt = 0; nt < 3; ++nt) {
                short8 bfr = *(const short8*)(const void*)
                    (W2bf + (size_t)(nt * 16 + l15) * 96 + kc * 32 + quad * 8);
                acc[nt] = __builtin_amdgcn_mfma_f32_16x16x32_bf16(af, bfr, acc[nt], 0, 0, 0);
            }
        }
#pragma unroll
        for (int nt = 0; nt < 3; ++nt) {
            int n = nt * 16 + l15;
            if (n < 40) {
                float bb = b2[n];
#pragma unroll
                for (int rg = 0; rg < 4; ++rg) {
                    int ml = wv * 16 + quad * 4 + rg;
                    z2sh[ml * 49 + n] = fast_tanh(acc[nt][rg] + bb);
                }
            }
        }
    }
    __syncthreads();

    if (tid < 64) {
        int grow = m0 + tid;
        float s = u[400] + otherp[grow] + otherp[BATCH + grow];
        for (int j = 0; j < 40; ++j) s = fmaf(z2sh[tid * 49 + j], W3[j], s);
        out[grow] = fast_sigmoid(s);
    }
}

extern "C" void kernel_launch(void* const* d_in, const int* in_sizes, int n_in,
                              void* d_out, int out_size, void* d_ws, size_t ws_size,
                              hipStream_t stream)
{
    const float* x = (const float*)d_in[0];
    LW w;
    for (int i = 0; i < 16; ++i) w.p[i] = (const float*)d_in[1 + i];
    const float* Wp = (const float*)d_in[17];
    const float* bp = (const float*)d_in[18];
    const float* WH = (const float*)d_in[19];
    const float* bH = (const float*)d_in[20];
    const float* WL = (const float*)d_in[21];
    const float* bL = (const float*)d_in[22];
    const float* W1 = (const float*)d_in[23];
    const float* b1 = (const float*)d_in[24];
    const float* W2 = (const float*)d_in[25];
    const float* b2 = (const float*)d_in[26];
    const float* W3 = (const float*)d_in[27];
    const float* b3 = (const float*)d_in[28];

    char* ws = (char*)d_ws;
    __hip_bfloat16* hh   = (__hip_bfloat16*)(ws + WS_HH);
    __hip_bfloat16* WHbf = (__hip_bfloat16*)(ws + WS_WHB);
    __hip_bfloat16* WLbf = (__hip_bfloat16*)(ws + WS_WLB);
    __hip_bfloat16* W1bf = (__hip_bfloat16*)(ws + WS_W1B);
    __hip_bfloat16* W2bf = (__hip_bfloat16*)(ws + WS_W2B);
    float* u      = (float*)(ws + WS_U);
    float* otherp = (float*)(ws + WS_OT);
    __hip_bfloat16* zws = (__hip_bfloat16*)(ws + WS_Z);
    float* out = (float*)d_out;

    k_prep<<<400, 256, 0, stream>>>(WH, WL, W1, W2, W3, Wp, bp, b3,
                                    WHbf, WLbf, W1bf, W2bf, u);
    k_lstm<<<1024, 256, 0, stream>>>(x, w, u, hh, otherp);
    k_gemm<<<dim3(256, 2), 256, 0, stream>>>(hh, WHbf, WLbf, bH, bL, zws);
    k_tail<<<512, 256, 0, stream>>>(zws, W1bf, W2bf, b1, b2, W3, u, otherp, out);
}